// Round 4
// baseline (1327.242 us; speedup 1.0000x reference)
//
#include <hip/hip_runtime.h>
#include <math.h>

#define L_ 64
#define LCHUNK 16            // l's per block (L split across gridDim.y = 4)
#define HPf 1.57079632679489661923f
#define TIE_THR 4e-3f        // fp32 perm-sum worst-case err ~4e-4 -> 10x margin

// fp32 9-way accumulate: cr[m][k] += a_m * b_k (compile-time indices)
#define CRF_STEP(a0, a1, a2, b0, b1, b2)                         \
    cr[0][0] = fmaf((a0), (b0), cr[0][0]);                       \
    cr[0][1] = fmaf((a0), (b1), cr[0][1]);                       \
    cr[0][2] = fmaf((a0), (b2), cr[0][2]);                       \
    cr[1][0] = fmaf((a1), (b0), cr[1][0]);                       \
    cr[1][1] = fmaf((a1), (b1), cr[1][1]);                       \
    cr[1][2] = fmaf((a1), (b2), cr[1][2]);                       \
    cr[2][0] = fmaf((a2), (b0), cr[2][0]);                       \
    cr[2][1] = fmaf((a2), (b1), cr[2][1]);                       \
    cr[2][2] = fmaf((a2), (b2), cr[2][2]);

// fp64 9-way accumulate into dr (rare tie-refinement path)
#define CRD_STEP(a0, a1, a2, b0, b1, b2)                         \
    dr[0][0] = fma((double)(a0), (double)(b0), dr[0][0]);        \
    dr[0][1] = fma((double)(a0), (double)(b1), dr[0][1]);        \
    dr[0][2] = fma((double)(a0), (double)(b2), dr[0][2]);        \
    dr[1][0] = fma((double)(a1), (double)(b0), dr[1][0]);        \
    dr[1][1] = fma((double)(a1), (double)(b1), dr[1][1]);        \
    dr[1][2] = fma((double)(a1), (double)(b2), dr[1][2]);        \
    dr[2][0] = fma((double)(a2), (double)(b0), dr[2][0]);        \
    dr[2][1] = fma((double)(a2), (double)(b1), dr[2][1]);        \
    dr[2][2] = fma((double)(a2), (double)(b2), dr[2][2]);

#define ER_STEP(a0, a1, a2, b0, b1, b2)                          \
    er[0][0] = fmaf((a0), (b0), er[0][0]);                       \
    er[0][1] = fmaf((a0), (b1), er[0][1]);                       \
    er[0][2] = fmaf((a0), (b2), er[0][2]);                       \
    er[1][0] = fmaf((a1), (b0), er[1][0]);                       \
    er[1][1] = fmaf((a1), (b1), er[1][1]);                       \
    er[1][2] = fmaf((a1), (b2), er[1][2]);                       \
    er[2][0] = fmaf((a2), (b0), er[2][0]);                       \
    er[2][1] = fmaf((a2), (b1), er[2][1]);                       \
    er[2][2] = fmaf((a2), (b2), er[2][2]);

// Fused kernel: all five scores per (l,n) in one pass.
// waves_per_eu(2,2): pins 2 waves/SIMD -> 256-VGPR budget. Live set ~190
// (xn 96 + ed 24 + xf 32 + accumulators + scalars), tie-branch peak ~225:
// fits, no spill. (Round 3's (2,4) hint allowed a 128-reg target -> 1.2 GB
// of scratch traffic; this is the single controlling variable here.)
__global__ __attribute__((amdgpu_waves_per_eu(2, 2))) __launch_bounds__(128)
void setconv_fused(const float* __restrict__ x_focal,
                   const float* __restrict__ p_focal,
                   const float* __restrict__ x_neighbor,
                   const float* __restrict__ p_neighbor,
                   const float* __restrict__ edge_nei,
                   const float* __restrict__ x_center,
                   const float* __restrict__ x_support,
                   const float* __restrict__ edge_sup,
                   const float* __restrict__ p_support,
                   float* __restrict__ out,
                   int N)
{
    __shared__ __align__(16) float s_xs[LCHUNK * 96];
    __shared__ __align__(16) float s_es[LCHUNK * 24];
    __shared__ __align__(16) float s_xc[LCHUNK * 32];
    __shared__ float s_scal[LCHUNK][12];

    const int tid = threadIdx.x;
    const int l0  = blockIdx.y * LCHUNK;

    for (int i = tid; i < LCHUNK * 96 / 4; i += 128)
        ((float4*)s_xs)[i] = ((const float4*)(x_support + (size_t)l0 * 96))[i];
    for (int i = tid; i < LCHUNK * 24 / 4; i += 128)
        ((float4*)s_es)[i] = ((const float4*)(edge_sup + (size_t)l0 * 24))[i];
    for (int i = tid; i < LCHUNK * 32 / 4; i += 128)
        ((float4*)s_xc)[i] = ((const float4*)(x_center + (size_t)l0 * 32))[i];
    __syncthreads();

    if (tid < LCHUNK) {
        const int l = l0 + tid;
        const float* row = s_xs + tid * 96;
        double ssq = 0.0;
        for (int i = 0; i < 96; ++i) { double v = (double)row[i]; ssq += v * v; }
        float esq = 0.f;
        for (int i = 0; i < 24; ++i) esq = fmaf(s_es[tid*24 + i], s_es[tid*24 + i], esq);
        float csq = 0.f;
        for (int i = 0; i < 32; ++i) csq = fmaf(s_xc[tid*32 + i], s_xc[tid*32 + i], csq);

        float p0[3], p1[3], p2[3];
        for (int d = 0; d < 3; ++d) {
            p0[d] = p_support[(l * 3 + 0) * 3 + d];
            p1[d] = p_support[(l * 3 + 1) * 3 + d];
            p2[d] = p_support[(l * 3 + 2) * 3 + d];
        }
        float n0 = sqrtf(p0[0]*p0[0] + p0[1]*p0[1] + p0[2]*p0[2]);
        float n1 = sqrtf(p1[0]*p1[0] + p1[1]*p1[1] + p1[2]*p1[2]);
        float n2 = sqrtf(p2[0]*p2[0] + p2[1]*p2[1] + p2[2]*p2[2]);
        float d01 = p0[0]*p1[0] + p0[1]*p1[1] + p0[2]*p1[2];
        float d02 = p0[0]*p2[0] + p0[1]*p2[1] + p0[2]*p2[2];
        float d12 = p1[0]*p2[0] + p1[1]*p2[1] + p1[2]*p2[2];
        float C01 = d01 / fmaxf(n0 * n1, 1e-8f);
        float C02 = d02 / fmaxf(n0 * n2, 1e-8f);
        float C12 = d12 / fmaxf(n1 * n2, 1e-8f);

        s_scal[tid][0] = n0;  s_scal[tid][1] = n1;  s_scal[tid][2] = n2;
        s_scal[tid][3] = C01; s_scal[tid][4] = C02; s_scal[tid][5] = C12;
        s_scal[tid][6] = C01*C01 + C02*C02 + C12*C12;  // ang_sup sq-sum (p-invariant)
        s_scal[tid][7] = n0*n0 + n1*n1 + n2*n2;        // len_sup sq-sum (p-invariant)
        s_scal[tid][8] = (float)ssq;                   // sup_sq
        s_scal[tid][9] = esq;
        s_scal[tid][10] = csq;
    }
    __syncthreads();

    const int n = blockIdx.x * 128 + tid;
    if (n >= N) return;

    // -------- per-n data into registers --------
    float4 xn4[24], ed4[6], xf4[8];
    {
        const float4* p = (const float4*)(x_neighbor + (size_t)n * 96);
        #pragma unroll
        for (int i = 0; i < 24; ++i) xn4[i] = p[i];
        const float4* q = (const float4*)(edge_nei + (size_t)n * 24);
        #pragma unroll
        for (int i = 0; i < 6; ++i) ed4[i] = q[i];
        const float4* r = (const float4*)(x_focal + (size_t)n * 32);
        #pragma unroll
        for (int i = 0; i < 8; ++i) xf4[i] = r[i];
    }

    float pr[3][3];
    {
        float pf0 = p_focal[(size_t)n*3 + 0];
        float pf1 = p_focal[(size_t)n*3 + 1];
        float pf2 = p_focal[(size_t)n*3 + 2];
        #pragma unroll
        for (int m = 0; m < 3; ++m) {
            pr[m][0] = p_neighbor[(size_t)n*9 + m*3 + 0] - pf0;
            pr[m][1] = p_neighbor[(size_t)n*9 + m*3 + 1] - pf1;
            pr[m][2] = p_neighbor[(size_t)n*9 + m*3 + 2] - pf2;
        }
    }
    float lenN0 = sqrtf(pr[0][0]*pr[0][0] + pr[0][1]*pr[0][1] + pr[0][2]*pr[0][2]);
    float lenN1 = sqrtf(pr[1][0]*pr[1][0] + pr[1][1]*pr[1][1] + pr[1][2]*pr[1][2]);
    float lenN2 = sqrtf(pr[2][0]*pr[2][0] + pr[2][1]*pr[2][1] + pr[2][2]*pr[2][2]);
    float angN0 = (pr[2][0]*pr[0][0] + pr[2][1]*pr[0][1] + pr[2][2]*pr[0][2]) / fmaxf(lenN2*lenN0, 1e-8f);
    float angN1 = (pr[0][0]*pr[1][0] + pr[0][1]*pr[1][1] + pr[0][2]*pr[1][2]) / fmaxf(lenN0*lenN1, 1e-8f);
    float angN2 = (pr[1][0]*pr[2][0] + pr[1][1]*pr[2][1] + pr[1][2]*pr[2][2]) / fmaxf(lenN1*lenN2, 1e-8f);
    float angN_sq = angN0*angN0 + angN1*angN1 + angN2*angN2;
    float lenN_sq = lenN0*lenN0 + lenN1*lenN1 + lenN2*lenN2;

    float nei_sq = 0.f, edsq = 0.f, xfsq = 0.f;
    #pragma unroll
    for (int i = 0; i < 24; ++i) {
        float4 v = xn4[i];
        nei_sq = fmaf(v.x, v.x, nei_sq); nei_sq = fmaf(v.y, v.y, nei_sq);
        nei_sq = fmaf(v.z, v.z, nei_sq); nei_sq = fmaf(v.w, v.w, nei_sq);
    }
    #pragma unroll
    for (int i = 0; i < 6; ++i) {
        float4 v = ed4[i];
        edsq = fmaf(v.x, v.x, edsq); edsq = fmaf(v.y, v.y, edsq);
        edsq = fmaf(v.z, v.z, edsq); edsq = fmaf(v.w, v.w, edsq);
    }
    #pragma unroll
    for (int i = 0; i < 8; ++i) {
        float4 v = xf4[i];
        xfsq = fmaf(v.x, v.x, xfsq); xfsq = fmaf(v.y, v.y, xfsq);
        xfsq = fmaf(v.z, v.z, xfsq); xfsq = fmaf(v.w, v.w, xfsq);
    }

    for (int ll = 0; ll < LCHUNK; ++ll) {
        const float* xs = s_xs + ll * 96;
        const float ssqf = s_scal[ll][8];

        // ---- 9 support dots, fp32 ----
        float cr[3][3] = {{0,0,0},{0,0,0},{0,0,0}};
        #pragma unroll
        for (int f4 = 0; f4 < 8; ++f4) {
            float4 B0 = ((const float4*)(xs +  0))[f4];
            float4 B1 = ((const float4*)(xs + 32))[f4];
            float4 B2 = ((const float4*)(xs + 64))[f4];
            float4 A0 = xn4[f4], A1 = xn4[8 + f4], A2 = xn4[16 + f4];
            CRF_STEP(A0.x, A1.x, A2.x, B0.x, B1.x, B2.x)
            CRF_STEP(A0.y, A1.y, A2.y, B0.y, B1.y, B2.y)
            CRF_STEP(A0.z, A1.z, A2.z, B0.z, B1.z, B2.z)
            CRF_STEP(A0.w, A1.w, A2.w, B0.w, B1.w, B2.w)
        }

        // perm sums (itertools order), packed byte a<<4|b<<2|c
        float c0 = cr[0][0] + cr[1][1] + cr[2][2];   // (0,1,2) -> 6
        float c1 = cr[0][0] + cr[1][2] + cr[2][1];   // (0,2,1) -> 9
        float c2 = cr[0][1] + cr[1][0] + cr[2][2];   // (1,0,2) -> 18
        float c3 = cr[0][1] + cr[1][2] + cr[2][0];   // (1,2,0) -> 24
        float c4 = cr[0][2] + cr[1][0] + cr[2][1];   // (2,0,1) -> 33
        float c5 = cr[0][2] + cr[1][1] + cr[2][0];   // (2,1,0) -> 36

        // first-max argmax with second-best tracking (strict >)
        float b1 = c0, b2 = -3.4e38f; int bpk = 6;
        if (c1 > b1) { b2 = b1; b1 = c1; bpk = 9;  } else if (c1 > b2) b2 = c1;
        if (c2 > b1) { b2 = b1; b1 = c2; bpk = 18; } else if (c2 > b2) b2 = c2;
        if (c3 > b1) { b2 = b1; b1 = c3; bpk = 24; } else if (c3 > b2) b2 = c3;
        if (c4 > b1) { b2 = b1; b1 = c4; bpk = 33; } else if (c4 > b2) b2 = c4;
        if (c5 > b1) { b2 = b1; b1 = c5; bpk = 36; } else if (c5 > b2) b2 = c5;

        float dist = nei_sq + ssqf - 2.0f * b1;

        if (b1 - b2 <= TIE_THR) {
            // rare near-tie: fp64 recompute settles ranking exactly
            double dr[3][3] = {{0,0,0},{0,0,0},{0,0,0}};
            #pragma unroll
            for (int f4 = 0; f4 < 8; ++f4) {
                float4 B0 = ((const float4*)(xs +  0))[f4];
                float4 B1 = ((const float4*)(xs + 32))[f4];
                float4 B2 = ((const float4*)(xs + 64))[f4];
                float4 A0 = xn4[f4], A1 = xn4[8 + f4], A2 = xn4[16 + f4];
                CRD_STEP(A0.x, A1.x, A2.x, B0.x, B1.x, B2.x)
                CRD_STEP(A0.y, A1.y, A2.y, B0.y, B1.y, B2.y)
                CRD_STEP(A0.z, A1.z, A2.z, B0.z, B1.z, B2.z)
                CRD_STEP(A0.w, A1.w, A2.w, B0.w, B1.w, B2.w)
            }
            double d0 = dr[0][0] + dr[1][1] + dr[2][2];
            double d1 = dr[0][0] + dr[1][2] + dr[2][1];
            double d2 = dr[0][1] + dr[1][0] + dr[2][2];
            double d3 = dr[0][1] + dr[1][2] + dr[2][0];
            double d4 = dr[0][2] + dr[1][0] + dr[2][1];
            double d5 = dr[0][2] + dr[1][1] + dr[2][0];
            double db = d0; bpk = 6;
            if (d1 > db) { db = d1; bpk = 9;  }
            if (d2 > db) { db = d2; bpk = 18; }
            if (d3 > db) { db = d3; bpk = 24; }
            if (d4 > db) { db = d4; bpk = 33; }
            if (d5 > db) { db = d5; bpk = 36; }
            dist = (float)((double)nei_sq + (double)ssqf - 2.0 * db);
        }

        // ---- value-only scores (fp32) ----
        const float* es = s_es + ll * 24;
        const float* xc = s_xc + ll * 32;

        float er[3][3] = {{0,0,0},{0,0,0},{0,0,0}};
        #pragma unroll
        for (int e4 = 0; e4 < 2; ++e4) {
            float4 B0 = ((const float4*)(es +  0))[e4];
            float4 B1 = ((const float4*)(es +  8))[e4];
            float4 B2 = ((const float4*)(es + 16))[e4];
            float4 A0 = ed4[e4], A1 = ed4[2 + e4], A2 = ed4[4 + e4];
            ER_STEP(A0.x, A1.x, A2.x, B0.x, B1.x, B2.x)
            ER_STEP(A0.y, A1.y, A2.y, B0.y, B1.y, B2.y)
            ER_STEP(A0.z, A1.z, A2.z, B0.z, B1.z, B2.z)
            ER_STEP(A0.w, A1.w, A2.w, B0.w, B1.w, B2.w)
        }

        float cdot = 0.f;
        #pragma unroll
        for (int f4 = 0; f4 < 8; ++f4) {
            float4 B = ((const float4*)xc)[f4];
            float4 A = xf4[f4];
            cdot = fmaf(A.x, B.x, cdot); cdot = fmaf(A.y, B.y, cdot);
            cdot = fmaf(A.z, B.z, cdot); cdot = fmaf(A.w, B.w, cdot);
        }

        int a = (bpk >> 4) & 3, b = (bpk >> 2) & 3, c = bpk & 3;

        float e0 = (a == 0) ? er[0][0] : ((a == 1) ? er[0][1] : er[0][2]);
        float e1 = (b == 0) ? er[1][0] : ((b == 1) ? er[1][1] : er[1][2]);
        float e2 = (c == 0) ? er[2][0] : ((c == 1) ? er[2][1] : er[2][2]);
        float bestE = e0 + e1 + e2;

        float n0 = s_scal[ll][0], n1 = s_scal[ll][1], n2 = s_scal[ll][2];
        float C01 = s_scal[ll][3], C02 = s_scal[ll][4], C12 = s_scal[ll][5];
        float la = (a == 0) ? n0 : ((a == 1) ? n1 : n2);
        float lb = (b == 0) ? n0 : ((b == 1) ? n1 : n2);
        float lc = (c == 0) ? n0 : ((c == 1) ? n1 : n2);
        float bestL = fmaf(lenN0, la, fmaf(lenN1, lb, lenN2 * lc));

        int sca = c + a, sab = a + b, sbc = b + c;            // in {1,2,3}
        float Cca = (sca == 1) ? C01 : ((sca == 2) ? C02 : C12);
        float Cab = (sab == 1) ? C01 : ((sab == 2) ? C02 : C12);
        float Cbc = (sbc == 1) ? C01 : ((sbc == 2) ? C02 : C12);
        float bestA = fmaf(angN0, Cca, fmaf(angN1, Cab, angN2 * Cbc));

        float sup_sc  = atanf(1.0f / dist);
        float edge_sc = atanf(1.0f / (edsq    + s_scal[ll][9]  - 2.0f * bestE));
        float ang_sc  = atanf(1.0f / (angN_sq + s_scal[ll][6]  - 2.0f * bestA));
        float len_sc  = atanf(1.0f / (lenN_sq + s_scal[ll][7]  - 2.0f * bestL));
        float cen_sc  = atanf(1.0f / (xfsq    + s_scal[ll][10] - 2.0f * cdot));

        float t1 = len_sc - HPf, t2 = ang_sc - HPf, t3 = sup_sc - HPf;
        float t4 = cen_sc - HPf, t5 = edge_sc - HPf;
        float h = t1*t1 + t2*t2 + t3*t3 + t4*t4 + t5*t5;
        out[(size_t)(l0 + ll) * N + n] = atanf(1.0f / h);
    }
}

extern "C" void kernel_launch(void* const* d_in, const int* in_sizes, int n_in,
                              void* d_out, int out_size, void* d_ws, size_t ws_size,
                              hipStream_t stream)
{
    const float* x_focal    = (const float*)d_in[0];
    const float* p_focal    = (const float*)d_in[1];
    const float* x_neighbor = (const float*)d_in[2];
    const float* p_neighbor = (const float*)d_in[3];
    const float* edge_nei   = (const float*)d_in[4];
    const float* x_center   = (const float*)d_in[5];
    const float* x_support  = (const float*)d_in[6];
    const float* edge_sup   = (const float*)d_in[7];
    const float* p_support  = (const float*)d_in[8];
    float* out = (float*)d_out;

    const int N = in_sizes[0] / 32;                // x_focal is (N, 32)
    const int threads = 128;
    dim3 grid((N + threads - 1) / threads, L_ / LCHUNK);

    setconv_fused<<<grid, threads, 0, stream>>>(
        x_focal, p_focal, x_neighbor, p_neighbor, edge_nei,
        x_center, x_support, edge_sup, p_support, out, N);
}

// Round 5
// 264.594 us; speedup vs baseline: 5.0162x; 5.0162x over previous
//
#include <hip/hip_runtime.h>
#include <math.h>

#define L_ 64
#define LCHUNK 16            // l's per block (L split across gridDim.y = 4)
#define HPf 1.57079632679489661923f
#define TIE_THR 4e-3f        // fp32 perm-sum worst-case err ~4e-4 -> 10x margin

// fp32 9-way accumulate: cr[m][k] += a_m * b_k (compile-time indices)
#define CRF_STEP(a0, a1, a2, b0, b1, b2)                         \
    cr[0][0] = fmaf((a0), (b0), cr[0][0]);                       \
    cr[0][1] = fmaf((a0), (b1), cr[0][1]);                       \
    cr[0][2] = fmaf((a0), (b2), cr[0][2]);                       \
    cr[1][0] = fmaf((a1), (b0), cr[1][0]);                       \
    cr[1][1] = fmaf((a1), (b1), cr[1][1]);                       \
    cr[1][2] = fmaf((a1), (b2), cr[1][2]);                       \
    cr[2][0] = fmaf((a2), (b0), cr[2][0]);                       \
    cr[2][1] = fmaf((a2), (b1), cr[2][1]);                       \
    cr[2][2] = fmaf((a2), (b2), cr[2][2]);

// ---------------- Kernel A: fp32 support argmax + tie worklist ----------------
// Live set ~120 VGPRs (xn 96 + 9 acc + temps) -> fits the 128-reg budget the
// allocator pins these kernels to (R1/R3/R4 evidence: any live set >128
// spills at VGPR_Count=128 regardless of waves_per_eu hints).
__global__ __launch_bounds__(128)
void setconvA(const float* __restrict__ x_neighbor,
              const float* __restrict__ x_support,
              float* __restrict__ out,
              unsigned char* __restrict__ bestp,
              int* __restrict__ wl_cnt,
              int* __restrict__ wl,
              int wl_cap,
              int N)
{
    __shared__ __align__(16) float s_xs[LCHUNK * 96];
    __shared__ float s_ssq[LCHUNK];

    const int tid = threadIdx.x;
    const int l0  = blockIdx.y * LCHUNK;

    for (int i = tid; i < LCHUNK * 24; i += 128)   // LCHUNK*96/4 float4's
        ((float4*)s_xs)[i] = ((const float4*)(x_support + (size_t)l0 * 96))[i];
    __syncthreads();
    if (tid < LCHUNK) {
        const float* row = s_xs + tid * 96;
        double ssq = 0.0;
        for (int i = 0; i < 96; ++i) { double v = (double)row[i]; ssq += v * v; }
        s_ssq[tid] = (float)ssq;
    }
    __syncthreads();

    const int n = blockIdx.x * 128 + tid;
    if (n >= N) return;

    float4 xn4[24];
    {
        const float4* p = (const float4*)(x_neighbor + (size_t)n * 96);
        #pragma unroll
        for (int i = 0; i < 24; ++i) xn4[i] = p[i];
    }
    float nei_sq = 0.f;
    #pragma unroll
    for (int i = 0; i < 24; ++i) {
        float4 v = xn4[i];
        nei_sq = fmaf(v.x, v.x, nei_sq); nei_sq = fmaf(v.y, v.y, nei_sq);
        nei_sq = fmaf(v.z, v.z, nei_sq); nei_sq = fmaf(v.w, v.w, nei_sq);
    }

    for (int ll = 0; ll < LCHUNK; ++ll) {
        const float* xs = s_xs + ll * 96;
        const float ssqf = s_ssq[ll];

        float cr[3][3] = {{0,0,0},{0,0,0},{0,0,0}};
        #pragma unroll
        for (int f4 = 0; f4 < 8; ++f4) {
            float4 B0 = ((const float4*)(xs +  0))[f4];
            float4 B1 = ((const float4*)(xs + 32))[f4];
            float4 B2 = ((const float4*)(xs + 64))[f4];
            float4 A0 = xn4[f4], A1 = xn4[8 + f4], A2 = xn4[16 + f4];
            CRF_STEP(A0.x, A1.x, A2.x, B0.x, B1.x, B2.x)
            CRF_STEP(A0.y, A1.y, A2.y, B0.y, B1.y, B2.y)
            CRF_STEP(A0.z, A1.z, A2.z, B0.z, B1.z, B2.z)
            CRF_STEP(A0.w, A1.w, A2.w, B0.w, B1.w, B2.w)
        }

        // perm sums (itertools order), packed byte a<<4|b<<2|c
        float c0 = cr[0][0] + cr[1][1] + cr[2][2];   // (0,1,2) -> 6
        float c1 = cr[0][0] + cr[1][2] + cr[2][1];   // (0,2,1) -> 9
        float c2 = cr[0][1] + cr[1][0] + cr[2][2];   // (1,0,2) -> 18
        float c3 = cr[0][1] + cr[1][2] + cr[2][0];   // (1,2,0) -> 24
        float c4 = cr[0][2] + cr[1][0] + cr[2][1];   // (2,0,1) -> 33
        float c5 = cr[0][2] + cr[1][1] + cr[2][0];   // (2,1,0) -> 36

        // first-max argmax with second-best tracking (strict >)
        float b1 = c0, b2 = -3.4e38f; int bpk = 6;
        if (c1 > b1) { b2 = b1; b1 = c1; bpk = 9;  } else if (c1 > b2) b2 = c1;
        if (c2 > b1) { b2 = b1; b1 = c2; bpk = 18; } else if (c2 > b2) b2 = c2;
        if (c3 > b1) { b2 = b1; b1 = c3; bpk = 24; } else if (c3 > b2) b2 = c3;
        if (c4 > b1) { b2 = b1; b1 = c4; bpk = 33; } else if (c4 > b2) b2 = c4;
        if (c5 > b1) { b2 = b1; b1 = c5; bpk = 36; } else if (c5 > b2) b2 = c5;

        float dist = nei_sq + ssqf - 2.0f * b1;
        float t3 = atanf(1.0f / dist) - HPf;
        size_t idx = (size_t)(l0 + ll) * N + n;
        out[idx]   = t3 * t3;
        bestp[idx] = (unsigned char)bpk;

        if (b1 - b2 <= TIE_THR) {
            int slot = atomicAdd(wl_cnt, 1);
            if (slot < wl_cap) wl[slot] = (int)idx;   // L*N < 2^31
        }
    }
}

// ---------------- Kernel A2: fp64 tie refinement (worklist) ----------------
__global__ __launch_bounds__(256)
void setconvA2(const float* __restrict__ x_neighbor,
               const float* __restrict__ x_support,
               float* __restrict__ out,
               unsigned char* __restrict__ bestp,
               const int* __restrict__ wl_cnt,
               const int* __restrict__ wl,
               int wl_cap,
               int N)
{
    int cnt = *wl_cnt; if (cnt > wl_cap) cnt = wl_cap;
    const int stride = gridDim.x * blockDim.x;
    for (int i = blockIdx.x * blockDim.x + threadIdx.x; i < cnt; i += stride) {
        const int idx = wl[i];
        const int l = idx / N;
        const int n = idx - l * N;
        const float* xn = x_neighbor + (size_t)n * 96;
        const float* xs = x_support  + (size_t)l * 96;

        double dr[3][3] = {{0,0,0},{0,0,0},{0,0,0}};
        double nei = 0.0, ssq = 0.0;
        for (int f = 0; f < 32; ++f) {
            double a0 = (double)xn[f], a1 = (double)xn[32 + f], a2 = (double)xn[64 + f];
            double b0 = (double)xs[f], b1 = (double)xs[32 + f], b2 = (double)xs[64 + f];
            dr[0][0] += a0 * b0; dr[0][1] += a0 * b1; dr[0][2] += a0 * b2;
            dr[1][0] += a1 * b0; dr[1][1] += a1 * b1; dr[1][2] += a1 * b2;
            dr[2][0] += a2 * b0; dr[2][1] += a2 * b1; dr[2][2] += a2 * b2;
            nei += a0 * a0 + a1 * a1 + a2 * a2;
            ssq += b0 * b0 + b1 * b1 + b2 * b2;
        }
        double d0 = dr[0][0] + dr[1][1] + dr[2][2];
        double d1 = dr[0][0] + dr[1][2] + dr[2][1];
        double d2 = dr[0][1] + dr[1][0] + dr[2][2];
        double d3 = dr[0][1] + dr[1][2] + dr[2][0];
        double d4 = dr[0][2] + dr[1][0] + dr[2][1];
        double d5 = dr[0][2] + dr[1][1] + dr[2][0];
        double db = d0; int bpk = 6;
        if (d1 > db) { db = d1; bpk = 9;  }
        if (d2 > db) { db = d2; bpk = 18; }
        if (d3 > db) { db = d3; bpk = 24; }
        if (d4 > db) { db = d4; bpk = 33; }
        if (d5 > db) { db = d5; bpk = 36; }

        float dist = (float)(nei + (double)((float)ssq) - 2.0 * db);
        float t3 = atanf(1.0f / dist) - HPf;
        out[idx]   = t3 * t3;
        bestp[idx] = (unsigned char)bpk;
    }
}

// ---------------- Kernel B: value-only scores (fp32, selective dots) --------
__global__ __launch_bounds__(128)
void setconvB(const float* __restrict__ x_focal,
              const float* __restrict__ p_focal,
              const float* __restrict__ p_neighbor,
              const float* __restrict__ edge_nei,
              const float* __restrict__ x_center,
              const float* __restrict__ edge_sup,
              const float* __restrict__ p_support,
              const unsigned char* __restrict__ bestp,
              float* __restrict__ out,
              int N)
{
    __shared__ __align__(16) float s_es[LCHUNK * 24];
    __shared__ __align__(16) float s_xc[LCHUNK * 32];
    __shared__ float s_scal[LCHUNK][10];

    const int tid = threadIdx.x;
    const int l0  = blockIdx.y * LCHUNK;

    for (int i = tid; i < LCHUNK * 6; i += 128)
        ((float4*)s_es)[i] = ((const float4*)(edge_sup + (size_t)l0 * 24))[i];
    for (int i = tid; i < LCHUNK * 8; i += 128)
        ((float4*)s_xc)[i] = ((const float4*)(x_center + (size_t)l0 * 32))[i];
    __syncthreads();

    if (tid < LCHUNK) {
        const int l = l0 + tid;
        float esq = 0.f;
        for (int i = 0; i < 24; ++i) esq = fmaf(s_es[tid*24 + i], s_es[tid*24 + i], esq);
        float csq = 0.f;
        for (int i = 0; i < 32; ++i) csq = fmaf(s_xc[tid*32 + i], s_xc[tid*32 + i], csq);

        float p0[3], p1[3], p2[3];
        for (int d = 0; d < 3; ++d) {
            p0[d] = p_support[(l * 3 + 0) * 3 + d];
            p1[d] = p_support[(l * 3 + 1) * 3 + d];
            p2[d] = p_support[(l * 3 + 2) * 3 + d];
        }
        float n0 = sqrtf(p0[0]*p0[0] + p0[1]*p0[1] + p0[2]*p0[2]);
        float n1 = sqrtf(p1[0]*p1[0] + p1[1]*p1[1] + p1[2]*p1[2]);
        float n2 = sqrtf(p2[0]*p2[0] + p2[1]*p2[1] + p2[2]*p2[2]);
        float d01 = p0[0]*p1[0] + p0[1]*p1[1] + p0[2]*p1[2];
        float d02 = p0[0]*p2[0] + p0[1]*p2[1] + p0[2]*p2[2];
        float d12 = p1[0]*p2[0] + p1[1]*p2[1] + p1[2]*p2[2];
        float C01 = d01 / fmaxf(n0 * n1, 1e-8f);
        float C02 = d02 / fmaxf(n0 * n2, 1e-8f);
        float C12 = d12 / fmaxf(n1 * n2, 1e-8f);

        s_scal[tid][0] = n0;  s_scal[tid][1] = n1;  s_scal[tid][2] = n2;
        s_scal[tid][3] = C01; s_scal[tid][4] = C02; s_scal[tid][5] = C12;
        s_scal[tid][6] = C01*C01 + C02*C02 + C12*C12;
        s_scal[tid][7] = n0*n0 + n1*n1 + n2*n2;
        s_scal[tid][8] = esq;
        s_scal[tid][9] = csq;
    }
    __syncthreads();

    const int n = blockIdx.x * 128 + tid;
    if (n >= N) return;

    float4 ed4[6], xf4[8];
    {
        const float4* q = (const float4*)(edge_nei + (size_t)n * 24);
        #pragma unroll
        for (int i = 0; i < 6; ++i) ed4[i] = q[i];
        const float4* r = (const float4*)(x_focal + (size_t)n * 32);
        #pragma unroll
        for (int i = 0; i < 8; ++i) xf4[i] = r[i];
    }

    float pr[3][3];
    {
        float pf0 = p_focal[(size_t)n*3 + 0];
        float pf1 = p_focal[(size_t)n*3 + 1];
        float pf2 = p_focal[(size_t)n*3 + 2];
        #pragma unroll
        for (int m = 0; m < 3; ++m) {
            pr[m][0] = p_neighbor[(size_t)n*9 + m*3 + 0] - pf0;
            pr[m][1] = p_neighbor[(size_t)n*9 + m*3 + 1] - pf1;
            pr[m][2] = p_neighbor[(size_t)n*9 + m*3 + 2] - pf2;
        }
    }
    float lenN0 = sqrtf(pr[0][0]*pr[0][0] + pr[0][1]*pr[0][1] + pr[0][2]*pr[0][2]);
    float lenN1 = sqrtf(pr[1][0]*pr[1][0] + pr[1][1]*pr[1][1] + pr[1][2]*pr[1][2]);
    float lenN2 = sqrtf(pr[2][0]*pr[2][0] + pr[2][1]*pr[2][1] + pr[2][2]*pr[2][2]);
    float angN0 = (pr[2][0]*pr[0][0] + pr[2][1]*pr[0][1] + pr[2][2]*pr[0][2]) / fmaxf(lenN2*lenN0, 1e-8f);
    float angN1 = (pr[0][0]*pr[1][0] + pr[0][1]*pr[1][1] + pr[0][2]*pr[1][2]) / fmaxf(lenN0*lenN1, 1e-8f);
    float angN2 = (pr[1][0]*pr[2][0] + pr[1][1]*pr[2][1] + pr[1][2]*pr[2][2]) / fmaxf(lenN1*lenN2, 1e-8f);
    float angN_sq = angN0*angN0 + angN1*angN1 + angN2*angN2;
    float lenN_sq = lenN0*lenN0 + lenN1*lenN1 + lenN2*lenN2;

    float edsq = 0.f, xfsq = 0.f;
    #pragma unroll
    for (int i = 0; i < 6; ++i) {
        float4 v = ed4[i];
        edsq = fmaf(v.x, v.x, edsq); edsq = fmaf(v.y, v.y, edsq);
        edsq = fmaf(v.z, v.z, edsq); edsq = fmaf(v.w, v.w, edsq);
    }
    #pragma unroll
    for (int i = 0; i < 8; ++i) {
        float4 v = xf4[i];
        xfsq = fmaf(v.x, v.x, xfsq); xfsq = fmaf(v.y, v.y, xfsq);
        xfsq = fmaf(v.z, v.z, xfsq); xfsq = fmaf(v.w, v.w, xfsq);
    }

    for (int ll = 0; ll < LCHUNK; ++ll) {
        const float* es = s_es + ll * 24;
        const float* xc = s_xc + ll * 32;

        size_t idx = (size_t)(l0 + ll) * N + n;
        int bp = bestp[idx];
        int a = (bp >> 4) & 3, b = (bp >> 2) & 3, c = bp & 3;

        // only the 3 SELECTED edge dots (24 FMA instead of 72); LDS row at
        // runtime offset is fine (indexed LDS read, no VGPR-array scratch)
        float bestE;
        {
            const float4* Ea = (const float4*)(es + a * 8);
            const float4* Eb = (const float4*)(es + b * 8);
            const float4* Ec = (const float4*)(es + c * 8);
            float e0 = 0.f, e1 = 0.f, e2 = 0.f;
            #pragma unroll
            for (int j = 0; j < 2; ++j) {
                float4 A0 = ed4[j], A1 = ed4[2 + j], A2 = ed4[4 + j];
                float4 B0 = Ea[j], B1 = Eb[j], B2 = Ec[j];
                e0 = fmaf(A0.x, B0.x, e0); e0 = fmaf(A0.y, B0.y, e0);
                e0 = fmaf(A0.z, B0.z, e0); e0 = fmaf(A0.w, B0.w, e0);
                e1 = fmaf(A1.x, B1.x, e1); e1 = fmaf(A1.y, B1.y, e1);
                e1 = fmaf(A1.z, B1.z, e1); e1 = fmaf(A1.w, B1.w, e1);
                e2 = fmaf(A2.x, B2.x, e2); e2 = fmaf(A2.y, B2.y, e2);
                e2 = fmaf(A2.z, B2.z, e2); e2 = fmaf(A2.w, B2.w, e2);
            }
            bestE = e0 + e1 + e2;
        }

        float cdot = 0.f;
        #pragma unroll
        for (int f4 = 0; f4 < 8; ++f4) {
            float4 B = ((const float4*)xc)[f4];
            float4 A = xf4[f4];
            cdot = fmaf(A.x, B.x, cdot); cdot = fmaf(A.y, B.y, cdot);
            cdot = fmaf(A.z, B.z, cdot); cdot = fmaf(A.w, B.w, cdot);
        }

        float n0 = s_scal[ll][0], n1 = s_scal[ll][1], n2 = s_scal[ll][2];
        float C01 = s_scal[ll][3], C02 = s_scal[ll][4], C12 = s_scal[ll][5];
        float la = (a == 0) ? n0 : ((a == 1) ? n1 : n2);
        float lb = (b == 0) ? n0 : ((b == 1) ? n1 : n2);
        float lc = (c == 0) ? n0 : ((c == 1) ? n1 : n2);
        float bestL = fmaf(lenN0, la, fmaf(lenN1, lb, lenN2 * lc));

        int sca = c + a, sab = a + b, sbc = b + c;            // in {1,2,3}
        float Cca = (sca == 1) ? C01 : ((sca == 2) ? C02 : C12);
        float Cab = (sab == 1) ? C01 : ((sab == 2) ? C02 : C12);
        float Cbc = (sbc == 1) ? C01 : ((sbc == 2) ? C02 : C12);
        float bestA = fmaf(angN0, Cca, fmaf(angN1, Cab, angN2 * Cbc));

        float edge_sc = atanf(1.0f / (edsq    + s_scal[ll][8] - 2.0f * bestE));
        float ang_sc  = atanf(1.0f / (angN_sq + s_scal[ll][6] - 2.0f * bestA));
        float len_sc  = atanf(1.0f / (lenN_sq + s_scal[ll][7] - 2.0f * bestL));
        float cen_sc  = atanf(1.0f / (xfsq    + s_scal[ll][9] - 2.0f * cdot));

        float t1 = len_sc - HPf, t2 = ang_sc - HPf, t4 = cen_sc - HPf, t5 = edge_sc - HPf;
        float h = out[idx] + t1*t1 + t2*t2 + t4*t4 + t5*t5;
        out[idx] = atanf(1.0f / h);
    }
}

extern "C" void kernel_launch(void* const* d_in, const int* in_sizes, int n_in,
                              void* d_out, int out_size, void* d_ws, size_t ws_size,
                              hipStream_t stream)
{
    const float* x_focal    = (const float*)d_in[0];
    const float* p_focal    = (const float*)d_in[1];
    const float* x_neighbor = (const float*)d_in[2];
    const float* p_neighbor = (const float*)d_in[3];
    const float* edge_nei   = (const float*)d_in[4];
    const float* x_center   = (const float*)d_in[5];
    const float* x_support  = (const float*)d_in[6];
    const float* edge_sup   = (const float*)d_in[7];
    const float* p_support  = (const float*)d_in[8];
    float* out = (float*)d_out;

    const int N = in_sizes[0] / 32;                // x_focal is (N, 32)
    const size_t LN = (size_t)L_ * (size_t)N;

    // d_ws layout: [0, LN) bestp bytes | [LN, LN+16) counter | worklist ints
    unsigned char* bestp = (unsigned char*)d_ws;
    int* wl_cnt = (int*)((char*)d_ws + LN);
    int* wl     = (int*)((char*)d_ws + LN + 16);
    long cap_l = ((long)ws_size - (long)LN - 16) / 4;
    int wl_cap = cap_l < 0 ? 0 : (cap_l > 2000000 ? 2000000 : (int)cap_l);

    hipMemsetAsync(wl_cnt, 0, sizeof(int), stream);

    const int threads = 128;
    dim3 grid((N + threads - 1) / threads, L_ / LCHUNK);

    setconvA<<<grid, threads, 0, stream>>>(x_neighbor, x_support, out, bestp,
                                           wl_cnt, wl, wl_cap, N);
    setconvA2<<<64, 256, 0, stream>>>(x_neighbor, x_support, out, bestp,
                                      wl_cnt, wl, wl_cap, N);
    setconvB<<<grid, threads, 0, stream>>>(x_focal, p_focal, p_neighbor, edge_nei,
                                           x_center, edge_sup, p_support, bestp, out, N);
}